// Round 4
// baseline (2420.069 us; speedup 1.0000x reference)
//
#include <hip/hip_runtime.h>

#define T_LEN 512
#define NB    32
#define HID4  1024
#define DSTR  ((size_t)T_LEN * NB * HID4)   // per-direction xg stride (elements)

#define EXCH_OFF  (64ull * 1024 * 1024)     // xg = 64 MiB
#define FLAGS_OFF (EXCH_OFF + 64ull * 1024) // exch data = 64 KiB
#define WS_NEED   (FLAGS_OFF + 2048ull)     // flags = 2 KiB

typedef short  bf16x8 __attribute__((ext_vector_type(8)));
typedef short  s16x4  __attribute__((ext_vector_type(4)));
typedef float  f32x4  __attribute__((ext_vector_type(4)));

static __device__ __forceinline__ unsigned short f2bf(float f) {
  union { float f; unsigned int i; } v; v.f = f;
  unsigned int r = v.i + 0x7FFFu + ((v.i >> 16) & 1u);
  return (unsigned short)(r >> 16);
}
static __device__ __forceinline__ unsigned short f2h(float f) {
  union { _Float16 h; unsigned short u; } v; v.h = (_Float16)f; return v.u;
}
static __device__ __forceinline__ float h2f(unsigned short u) {
  union { unsigned short u; _Float16 h; } v; v.u = u; return (float)v.h;
}
static __device__ __forceinline__ float sigm(float x) {
  return __builtin_amdgcn_rcpf(1.0f + __builtin_amdgcn_exp2f(-1.44269504f * x));
}
static __device__ __forceinline__ float tanh_fast(float x) {
  float e = __builtin_amdgcn_exp2f(2.885390082f * x);
  return 1.0f - 2.0f * __builtin_amdgcn_rcpf(e + 1.0f);
}
static __device__ __forceinline__ bf16x8 cvt8(const float* p) {
  bf16x8 r;
  #pragma unroll
  for (int i = 0; i < 8; ++i) r[i] = (short)f2bf(p[i]);
  return r;
}
// 16B from the L3-coherent exchange buffer: 4 device-scope dword loads
static __device__ __forceinline__ bf16x8 ld_exch16(const unsigned short* p) {
  const unsigned int* q = (const unsigned int*)p;
  union { unsigned int u[4]; bf16x8 v; } r;
  #pragma unroll
  for (int i = 0; i < 4; ++i)
    r.u[i] = __hip_atomic_load(q + i, __ATOMIC_RELAXED, __HIP_MEMORY_SCOPE_AGENT);
  return r.v;
}

// ---------------------------------------------------------------------------
// GEMM: xg = A @ W^T + bias, written in the rec-thread layout:
//   xg[dir][t][bg(8)][tid10(1024)][c(4)]  (f16), c = gt
//   tid10 = (j>>4)*64 + (b&3)*16 + (j&15)
// Each recurrence thread reads its 4 gate-values as ONE 8B load.
// ---------------------------------------------------------------------------
__global__ __launch_bounds__(256) void gemm_xg(
    const float* __restrict__ A,
    const float* __restrict__ Wf,
    const float* __restrict__ Wb,
    const float* __restrict__ biasf,
    const float* __restrict__ biasb,
    unsigned short* __restrict__ out, int K)
{
  __shared__ __align__(16) unsigned short As[64][40];
  __shared__ __align__(16) unsigned short Bs[64][40];

  const int dir = blockIdx.z;
  const float* W    = dir ? Wb    : Wf;
  const float* bias = dir ? biasb : biasf;
  unsigned short* outd = out + (size_t)dir * DSTR;

  const int m0 = blockIdx.x * 64;
  const int n0 = blockIdx.y * 64;
  const int tid = threadIdx.x;
  const int wv = tid >> 6, lane = tid & 63;
  const int lm = lane & 15, lq = lane >> 4;
  const int mt0 = (wv >> 1) * 32, nt0 = (wv & 1) * 32;
  const int lr = tid >> 2, ls = tid & 3;

  f32x4 acc[2][2];
  #pragma unroll
  for (int a = 0; a < 2; ++a)
    #pragma unroll
    for (int b = 0; b < 2; ++b) acc[a][b] = (f32x4){0.f, 0.f, 0.f, 0.f};

  for (int kc = 0; kc < K; kc += 32) {
    *(bf16x8*)&As[lr][ls * 8] = cvt8(A + (size_t)(m0 + lr) * K + kc + ls * 8);
    *(bf16x8*)&Bs[lr][ls * 8] = cvt8(W + (size_t)(n0 + lr) * K + kc + ls * 8);
    __syncthreads();
    bf16x8 af[2], bfr[2];
    af[0]  = *(const bf16x8*)&As[mt0 + lm][lq * 8];
    af[1]  = *(const bf16x8*)&As[mt0 + 16 + lm][lq * 8];
    bfr[0] = *(const bf16x8*)&Bs[nt0 + lm][lq * 8];
    bfr[1] = *(const bf16x8*)&Bs[nt0 + 16 + lm][lq * 8];
    #pragma unroll
    for (int mt = 0; mt < 2; ++mt)
      #pragma unroll
      for (int nt = 0; nt < 2; ++nt)
        acc[mt][nt] = __builtin_amdgcn_mfma_f32_16x16x32_bf16(af[mt], bfr[nt], acc[mt][nt], 0, 0, 0);
    __syncthreads();
  }

  #pragma unroll
  for (int nt = 0; nt < 2; ++nt) {
    const int n = n0 + nt0 + nt * 16 + lm;       // gate index 0..1023
    const float bv = bias[n];
    const int gt = n >> 8, j = n & 255;
    const int tidbase = (j >> 4) * 64 + (j & 15);
    #pragma unroll
    for (int mt = 0; mt < 2; ++mt)
      #pragma unroll
      for (int r4 = 0; r4 < 4; ++r4) {
        const int m = m0 + mt0 + mt * 16 + lq * 4 + r4;   // token = b*T + t
        const int b = m >> 9, t = m & 511;
        const int bg = b >> 2, lqr = b & 3;
        outd[((((size_t)t * 8 + bg) * 1024 + tidbase + lqr * 16) << 2) + gt] =
            f2h(acc[mt][nt][r4] + bv);
      }
  }
}

// ---------------------------------------------------------------------------
// j-split recurrence. Grid = 32 blocks: (dir, bg, half). Each block computes
// gates for j in [half*128, half*128+128) -> 512 gate-rows, K=256 full.
// W fully register-resident (breg[4][8] = 128 VGPR): ZERO B-LDS traffic.
// MFMA floor halves: 256 instr/step (~1240 cy) vs 512 in the unsplit kernel.
// Pair (blockIdx ^ 1) exchanges its 1 KB h-half per step via an L3-coherent
// buffer (device-scope atomics) + monotone per-half flags:
//   producer: pack->store(sc1) -> vmcnt drain -> barrier -> flag = base+s+1
//   consumer: lane0 spin flag >= base+s -> 16 dword loads (hidden under
//             own-half MFMAs) -> partner MFMAs from regs.
// 2-buffer ping-pong is race-free: a block can't start overwriting parity p
// before its partner's flag for the step that consumed p (proof: flag order).
// Flags are monotone across layers (base 0 / 512); memset once per launch.
// ---------------------------------------------------------------------------
__global__ __launch_bounds__(512) __attribute__((amdgpu_waves_per_eu(2, 2)))
void lstm_rec_split(
    const unsigned short* __restrict__ xg,   // [2][T][8][1024][4] f16
    const float* __restrict__ whh_f,         // [1024][256] f32
    const float* __restrict__ whh_b,
    float* __restrict__ out,                 // [32][T][512] f32, col off dir*256
    unsigned short* __restrict__ exch,       // [2][8][2][2 par][512] bf16
    unsigned int* __restrict__ flags,        // [2][8][2] x 16 dwords (padded)
    int flag_base)
{
  __shared__ __align__(16) unsigned short hbuf[4096];  // [par2][kt4][q4][m16][e8]

  const int dir  = blockIdx.x >> 4;
  const int bg   = (blockIdx.x >> 1) & 7;
  const int half = blockIdx.x & 1;
  const int b0 = bg * 4;
  const float* whh = dir ? whh_b : whh_f;
  const unsigned short* xgd = xg + (size_t)dir * DSTR;
  const int wave = threadIdx.x >> 6, lane = threadIdx.x & 63;
  const int lm = lane & 15, lq = lane >> 4;
  const int j0 = half * 128 + wave * 16;     // this wave's 16 j-cols

  // ---- W_hh fragments: breg[gt][0..3] = own kts, [4..7] = partner kts ----
  bf16x8 breg[4][8];
  #pragma unroll
  for (int gt = 0; gt < 4; ++gt) {
    const float* wrow = whh + (size_t)(gt * 256 + j0 + lm) * 256;
    #pragma unroll
    for (int i = 0; i < 8; ++i) {
      const int gkt = (i < 4) ? (half * 4 + i) : ((half ^ 1) * 4 + (i - 4));
      breg[gt][i] = cvt8(wrow + gkt * 32 + lq * 8);
    }
  }

  for (int i = threadIdx.x; i < 4096; i += 512) hbuf[i] = 0;

  float creg = 0.f;
  const int j = j0 + lm;                               // this thread's hidden col
  float* obase = out + (size_t)(b0 + lq) * T_LEN * 512 + dir * 256 + j;
  // own h slots (kt-relative within own half)
  const int wb  = ((j >> 5) & 3) * 512 + ((j >> 3) & 3) * 128 + lq * 32 + (j & 7);
  const int exw = ((j >> 5) & 3) * 128 + ((j >> 3) & 3) * 32  + lq * 8  + (j & 7);
  unsigned short* exown =
      exch + (size_t)(((dir * 8 + bg) * 2 + half) * 2) * 512;
  const unsigned short* expar =
      exch + (size_t)(((dir * 8 + bg) * 2 + (half ^ 1)) * 2) * 512;
  unsigned int* flagown = flags + ((dir * 8 + bg) * 2 + half) * 16;
  unsigned int* flagpar = flags + ((dir * 8 + bg) * 2 + (half ^ 1)) * 16;
  // partner-read base: quad-broadcast (4 lanes same addr), rows 4k real
  const int prd = lq * 32 + ((lane & 15) >> 2) * 8;

  __syncthreads();

  for (int s = 0; s < T_LEN; ++s) {
    const int tt = dir ? (T_LEN - 1 - s) : s;
    const unsigned short* hr = hbuf + (s & 1) * 2048;
    unsigned short* hw = hbuf + ((s + 1) & 1) * 2048;

    const s16x4 xq = *(const s16x4*)(
        xgd + ((((size_t)tt * 8 + bg) * 1024 + half * 512 + threadIdx.x) << 2));

    f32x4 acc[4];
    #pragma unroll
    for (int gt = 0; gt < 4; ++gt) acc[gt] = (f32x4){0.f, 0.f, 0.f, 0.f};

    if (s > 0) {
      // wait for partner's h_{s-1}
      const unsigned want = (unsigned)(flag_base + s);
      if (lane == 0) {
        while (__hip_atomic_load(flagpar, __ATOMIC_RELAXED, __HIP_MEMORY_SCOPE_AGENT) < want)
          __builtin_amdgcn_s_sleep(2);
      }
      // issue partner loads early; latency hides under own-half MFMAs
      const unsigned short* ex = expar + (s & 1) * 512;
      bf16x8 pfr[4];
      #pragma unroll
      for (int r = 0; r < 4; ++r) pfr[r] = ld_exch16(ex + r * 128 + prd);

      // own-half MFMAs (A from LDS, padded conflict-free layout)
      #pragma unroll
      for (int r = 0; r < 4; ++r) {
        const bf16x8 afrag = *(const bf16x8*)(hr + r * 512 + lane * 8);
        #pragma unroll
        for (int gt = 0; gt < 4; ++gt)
          acc[gt] = __builtin_amdgcn_mfma_f32_16x16x32_bf16(afrag, breg[gt][r], acc[gt], 0, 0, 0);
      }
      // partner-half MFMAs (A from regs; garbage rows != 4k are never read)
      #pragma unroll
      for (int r = 0; r < 4; ++r)
        #pragma unroll
        for (int gt = 0; gt < 4; ++gt)
          acc[gt] = __builtin_amdgcn_mfma_f32_16x16x32_bf16(pfr[r], breg[gt][4 + r], acc[gt], 0, 0, 0);
    }

    // gate math: one h per thread (batch b0+lq, col j)
    const float iv = sigm(acc[0][0] + h2f((unsigned short)xq[0]));
    const float fv = sigm(acc[1][0] + h2f((unsigned short)xq[1]));
    const float gv = tanh_fast(acc[2][0] + h2f((unsigned short)xq[2]));
    const float ov = sigm(acc[3][0] + h2f((unsigned short)xq[3]));
    const float cv = fv * creg + iv * gv;
    creg = cv;
    const float hv = ov * tanh_fast(cv);

    hw[wb] = f2bf(hv);

    // publish own half: lane-pairs pack 2 bf16 into one device-scope dword
    const unsigned hb = (unsigned)f2bf(hv);
    const unsigned nb = (unsigned)__shfl_xor((int)hb, 1);
    if ((lane & 1) == 0) {
      const unsigned pk = (hb & 0xffffu) | (nb << 16);
      __hip_atomic_store((unsigned int*)(exown + ((s + 1) & 1) * 512 + exw), pk,
                         __ATOMIC_RELAXED, __HIP_MEMORY_SCOPE_AGENT);
    }
    asm volatile("" ::: "memory");            // pin exch-store before out-store
    obase[(size_t)tt * 512] = hv;

    asm volatile("s_waitcnt vmcnt(1)" ::: "memory");   // exch drained; out may fly
    asm volatile("s_waitcnt lgkmcnt(0)" ::: "memory"); // h LDS visible
    __builtin_amdgcn_s_barrier();
    asm volatile("" ::: "memory");
    if (threadIdx.x == 0)
      __hip_atomic_store(flagown, (unsigned)(flag_base + s + 1),
                         __ATOMIC_RELAXED, __HIP_MEMORY_SCOPE_AGENT);
  }
}

// ---------------------------------------------------------------------------
// Fallback (ws too small for exchange region): R2-structure 16-block kernel
// adapted to the c(4) xg layout. Known-good ~880 us/dispatch behavior.
// ---------------------------------------------------------------------------
__global__ __launch_bounds__(512) __attribute__((amdgpu_waves_per_eu(2, 2)))
void lstm_rec_fb(
    const unsigned short* __restrict__ xg,   // [2][T][8][1024][4] f16
    const float* __restrict__ whh_f,
    const float* __restrict__ whh_b,
    float* __restrict__ out)
{
  __shared__ __align__(16) unsigned short ldsB[65536];
  __shared__ __align__(16) unsigned short hbuf[8192];

  const int dir = blockIdx.x >> 3, bg = blockIdx.x & 7;
  const int b0 = bg * 4;
  const float* whh = dir ? whh_b : whh_f;
  const unsigned short* xgd = xg + (size_t)dir * DSTR;
  const int wave = threadIdx.x >> 6, lane = threadIdx.x & 63;
  const int lm = lane & 15, lq = lane >> 4;
  const int j0 = wave * 32;

  bf16x8 breg[4][2][6];
  #pragma unroll
  for (int gt = 0; gt < 4; ++gt)
    #pragma unroll
    for (int nh = 0; nh < 2; ++nh) {
      const float* wrow = whh + (size_t)(gt * 256 + j0 + nh * 16 + lm) * 256;
      #pragma unroll
      for (int kt = 0; kt < 6; ++kt)
        breg[gt][nh][kt] = cvt8(wrow + kt * 32 + lq * 8);
      #pragma unroll
      for (int kt = 6; kt < 8; ++kt) {
        const int tl = wave * 16 + gt * 4 + nh * 2 + (kt - 6);
        *(bf16x8*)(ldsB + ((size_t)tl * 64 + lane) * 8) = cvt8(wrow + kt * 32 + lq * 8);
      }
    }

  for (int i = threadIdx.x; i < 8192; i += 512) hbuf[i] = 0;
  float creg[2] = {0.f, 0.f};
  float* obase = out + (size_t)(b0 + lq) * T_LEN * 512 + dir * 256 + j0 + lm;
  const int wb0 = wave * 512 + (lm >> 3) * 128 + lq * 32 + (lm & 7);

  __syncthreads();

  for (int s = 0; s < T_LEN; ++s) {
    const int tt = dir ? (T_LEN - 1 - s) : s;
    const unsigned short* hr = hbuf + (s & 1) * 4096;
    unsigned short* hw = hbuf + ((s + 1) & 1) * 4096;

    const unsigned short* xp = xgd + ((((size_t)tt * 8 + bg) * 1024) << 2);
    const s16x4 xqa = *(const s16x4*)(xp + (((wave * 2 + 0) * 64 + lq * 16 + lm) << 2));
    const s16x4 xqb = *(const s16x4*)(xp + (((wave * 2 + 1) * 64 + lq * 16 + lm) << 2));

    f32x4 acc[2][4];
    #pragma unroll
    for (int nh = 0; nh < 2; ++nh)
      #pragma unroll
      for (int gt = 0; gt < 4; ++gt) acc[nh][gt] = (f32x4){0.f, 0.f, 0.f, 0.f};

    #pragma unroll
    for (int kt = 0; kt < 8; ++kt) {
      const bf16x8 afrag = *(const bf16x8*)(hr + kt * 512 + lane * 8);
      #pragma unroll
      for (int nh = 0; nh < 2; ++nh)
        #pragma unroll
        for (int gt = 0; gt < 4; ++gt) {
          bf16x8 bfr;
          if (kt < 6) bfr = breg[gt][nh][kt];
          else        bfr = *(const bf16x8*)(ldsB + ((size_t)(wave * 16 + gt * 4 + nh * 2 + (kt - 6)) * 64 + lane) * 8);
          acc[nh][gt] = __builtin_amdgcn_mfma_f32_16x16x32_bf16(afrag, bfr, acc[nh][gt], 0, 0, 0);
        }
    }

    const size_t tto = (size_t)tt * 512;
    #pragma unroll
    for (int nh = 0; nh < 2; ++nh) {
      const s16x4 xq = nh ? xqb : xqa;
      const float iv = sigm(acc[nh][0][0] + h2f((unsigned short)xq[0]));
      const float fv = sigm(acc[nh][1][0] + h2f((unsigned short)xq[1]));
      const float gv = tanh_fast(acc[nh][2][0] + h2f((unsigned short)xq[2]));
      const float ov = sigm(acc[nh][3][0] + h2f((unsigned short)xq[3]));
      const float cv = fv * creg[nh] + iv * gv;
      creg[nh] = cv;
      const float hv = ov * tanh_fast(cv);
      hw[wb0 + nh * 256] = f2bf(hv);
      obase[tto + nh * 16] = hv;
    }

    asm volatile("s_waitcnt lgkmcnt(0)" ::: "memory");
    __builtin_amdgcn_s_barrier();
    asm volatile("" ::: "memory");
  }
}

// ---------------------------------------------------------------------------
extern "C" void kernel_launch(void* const* d_in, const int* in_sizes, int n_in,
                              void* d_out, int out_size, void* d_ws, size_t ws_size,
                              hipStream_t stream) {
  const float* x     = (const float*)d_in[0];
  const float* wih0f = (const float*)d_in[1];
  const float* whh0f = (const float*)d_in[2];
  const float* b0f   = (const float*)d_in[3];
  const float* wih0b = (const float*)d_in[4];
  const float* whh0b = (const float*)d_in[5];
  const float* b0b   = (const float*)d_in[6];
  const float* wih1f = (const float*)d_in[7];
  const float* whh1f = (const float*)d_in[8];
  const float* b1f   = (const float*)d_in[9];
  const float* wih1b = (const float*)d_in[10];
  const float* whh1b = (const float*)d_in[11];
  const float* b1b   = (const float*)d_in[12];
  float* out = (float*)d_out;

  unsigned short* xg = (unsigned short*)d_ws;

  if (ws_size >= WS_NEED) {
    unsigned short* exch = (unsigned short*)((char*)d_ws + EXCH_OFF);
    unsigned int* flags  = (unsigned int*)((char*)d_ws + FLAGS_OFF);
    hipMemsetAsync(flags, 0, 2048, stream);
    gemm_xg<<<dim3(256, 16, 2), 256, 0, stream>>>(x,   wih0f, wih0b, b0f, b0b, xg, 256);
    lstm_rec_split<<<32, 512, 0, stream>>>(xg, whh0f, whh0b, out, exch, flags, 0);
    gemm_xg<<<dim3(256, 16, 2), 256, 0, stream>>>(out, wih1f, wih1b, b1f, b1b, xg, 512);
    lstm_rec_split<<<32, 512, 0, stream>>>(xg, whh1f, whh1b, out, exch, flags, 512);
  } else {
    gemm_xg<<<dim3(256, 16, 2), 256, 0, stream>>>(x,   wih0f, wih0b, b0f, b0b, xg, 256);
    lstm_rec_fb<<<16, 512, 0, stream>>>(xg, whh0f, whh0b, out);
    gemm_xg<<<dim3(256, 16, 2), 256, 0, stream>>>(out, wih1f, wih1b, b1f, b1b, xg, 512);
    lstm_rec_fb<<<16, 512, 0, stream>>>(xg, whh1f, whh1b, out);
  }
}

// Round 5
// 1838.492 us; speedup vs baseline: 1.3163x; 1.3163x over previous
//
#include <hip/hip_runtime.h>

#define T_LEN 512
#define NB    32
#define HID4  1024
#define DSTR  ((size_t)T_LEN * NB * HID4)   // per-direction xg stride (elements)

typedef short  bf16x8 __attribute__((ext_vector_type(8)));
typedef float  f32x4  __attribute__((ext_vector_type(4)));

static __device__ __forceinline__ unsigned short f2bf(float f) {
  union { float f; unsigned int i; } v; v.f = f;
  unsigned int r = v.i + 0x7FFFu + ((v.i >> 16) & 1u);
  return (unsigned short)(r >> 16);
}
static __device__ __forceinline__ unsigned short f2h(float f) {
  union { _Float16 h; unsigned short u; } v; v.h = (_Float16)f; return v.u;
}
static __device__ __forceinline__ float h2f(unsigned short u) {
  union { unsigned short u; _Float16 h; } v; v.u = u; return (float)v.h;
}
static __device__ __forceinline__ float sigm(float x) {
  return __builtin_amdgcn_rcpf(1.0f + __builtin_amdgcn_exp2f(-1.44269504f * x));
}
static __device__ __forceinline__ float tanh_fast(float x) {
  float e = __builtin_amdgcn_exp2f(2.885390082f * x);
  return 1.0f - 2.0f * __builtin_amdgcn_rcpf(e + 1.0f);
}
// convert 8 consecutive f32 -> bf16x8
static __device__ __forceinline__ bf16x8 cvt8(const float* p) {
  bf16x8 r;
  #pragma unroll
  for (int i = 0; i < 8; ++i) r[i] = (short)f2bf(p[i]);
  return r;
}

// ---------------------------------------------------------------------------
// GEMM: xg = A @ W^T + bias, written in the rec-thread-swizzled layout:
//   xg[dir][t][bg(8)][tid(512)][c(8)]  (f16), c = nh*4 + gt
// Each recurrence thread reads its 8 gate-values as ONE 16B load.
// A: f32 [16384][K], W: f32 [1024][K]. 64x64 tile, 4 waves, K-chunks of 32.
// (R2-exact: best-measured pairing with the 16-block recurrence.)
// ---------------------------------------------------------------------------
__global__ __launch_bounds__(256) void gemm_xg(
    const float* __restrict__ A,
    const float* __restrict__ Wf,
    const float* __restrict__ Wb,
    const float* __restrict__ biasf,
    const float* __restrict__ biasb,
    unsigned short* __restrict__ out, int K)
{
  __shared__ __align__(16) unsigned short As[64][40];
  __shared__ __align__(16) unsigned short Bs[64][40];

  const int dir = blockIdx.z;
  const float* W    = dir ? Wb    : Wf;
  const float* bias = dir ? biasb : biasf;
  unsigned short* outd = out + (size_t)dir * DSTR;

  const int m0 = blockIdx.x * 64;
  const int n0 = blockIdx.y * 64;
  const int tid = threadIdx.x;
  const int wv = tid >> 6, lane = tid & 63;
  const int lm = lane & 15, lq = lane >> 4;
  const int mt0 = (wv >> 1) * 32, nt0 = (wv & 1) * 32;
  const int lr = tid >> 2, ls = tid & 3;

  f32x4 acc[2][2];
  #pragma unroll
  for (int a = 0; a < 2; ++a)
    #pragma unroll
    for (int b = 0; b < 2; ++b) acc[a][b] = (f32x4){0.f, 0.f, 0.f, 0.f};

  for (int kc = 0; kc < K; kc += 32) {
    *(bf16x8*)&As[lr][ls * 8] = cvt8(A + (size_t)(m0 + lr) * K + kc + ls * 8);
    *(bf16x8*)&Bs[lr][ls * 8] = cvt8(W + (size_t)(n0 + lr) * K + kc + ls * 8);
    __syncthreads();
    bf16x8 af[2], bfr[2];
    af[0]  = *(const bf16x8*)&As[mt0 + lm][lq * 8];
    af[1]  = *(const bf16x8*)&As[mt0 + 16 + lm][lq * 8];
    bfr[0] = *(const bf16x8*)&Bs[nt0 + lm][lq * 8];
    bfr[1] = *(const bf16x8*)&Bs[nt0 + 16 + lm][lq * 8];
    #pragma unroll
    for (int mt = 0; mt < 2; ++mt)
      #pragma unroll
      for (int nt = 0; nt < 2; ++nt)
        acc[mt][nt] = __builtin_amdgcn_mfma_f32_16x16x32_bf16(af[mt], bfr[nt], acc[mt][nt], 0, 0, 0);
    __syncthreads();
  }

  #pragma unroll
  for (int nt = 0; nt < 2; ++nt) {
    const int n = n0 + nt0 + nt * 16 + lm;       // gate index 0..1023
    const float bv = bias[n];
    const int gt = n >> 8, j = n & 255;
    const int wvr = j >> 5, nh = (j >> 4) & 1, lmr = j & 15;
    const int c = nh * 4 + gt;
    #pragma unroll
    for (int mt = 0; mt < 2; ++mt)
      #pragma unroll
      for (int r4 = 0; r4 < 4; ++r4) {
        const int m = m0 + mt0 + mt * 16 + lq * 4 + r4;   // token = b*T + t
        const int b = m >> 9, t = m & 511;
        const int bg = b >> 2, lqr = b & 3;               // batch-group, local batch
        const int tidr = wvr * 64 + lqr * 16 + lmr;       // recurrence thread id
        outd[((((size_t)t * 8 + bg) * 512 + tidr) << 3) + c] = f2h(acc[mt][nt][r4] + bv);
      }
  }
}

// ---------------------------------------------------------------------------
// Recurrence. Grid = 16 blocks (dir*8 + batch-group of 4), 512 threads (8 waves).
// R2 structure (best measured: 877us/dispatch) + three changes:
//  (1) gt-outer MFMA order with A-frags in regs (ar[6]): each nh-pass's
//      acc[gt] finishes after its own chain -> gate VALU for nh=0 hides
//      under nh=1's MFMAs; serial tail ~300cy -> ~80cy.
//  (2) LDS-resident kts (6,7) FIRST in each pass: their B-frag reads issue
//      right after the barrier, latency hidden under reg-kt MFMAs.
//      (R3 had this too; R3's regression was the compact-A bank conflicts,
//      reverted here - padded conflict-free hbuf layout restored.)
//  (3) s_setprio(1/0) around MFMA clusters.
// Reg budget (waves_per_eu(2,2) -> 256): breg 192 + ar 24 + acc 16 + xq 8
// + misc ~ 250. Watch VGPR_Count for spill.
// Barrier: raw s_barrier + lgkmcnt(0) only (no vmcnt drain); xq prefetched
// one step ahead (R2-faithful).
// ---------------------------------------------------------------------------
__global__ __launch_bounds__(512) __attribute__((amdgpu_waves_per_eu(2, 2)))
void lstm_rec(
    const unsigned short* __restrict__ xg,   // [2][T][8][512][8] f16 (swizzled)
    const float* __restrict__ whh_f,         // [1024][256] f32
    const float* __restrict__ whh_b,
    float* __restrict__ out)                 // [32][T][512] f32, col off dir*256
{
  __shared__ __align__(16) unsigned short ldsB[65536];  // 128 frags * 1 KB
  __shared__ __align__(16) unsigned short hbuf[8192];   // [2][8][4][16][8]

  const int dir = blockIdx.x >> 3, bg = blockIdx.x & 7;
  const int b0 = bg * 4;
  const float* whh = dir ? whh_b : whh_f;
  const unsigned short* xgd = xg + (size_t)dir * DSTR;
  const int wave = threadIdx.x >> 6, lane = threadIdx.x & 63;
  const int lm = lane & 15, lq = lane >> 4;
  const int j0 = wave * 32;

  // ---- preload W_hh fragments (B-operand: n = lane&15, k = lq*8 + j) ----
  bf16x8 breg[4][2][6];
  #pragma unroll
  for (int gt = 0; gt < 4; ++gt)
    #pragma unroll
    for (int nh = 0; nh < 2; ++nh) {
      const float* wrow = whh + (size_t)(gt * 256 + j0 + nh * 16 + lm) * 256;
      #pragma unroll
      for (int kt = 0; kt < 6; ++kt)
        breg[gt][nh][kt] = cvt8(wrow + kt * 32 + lq * 8);
      #pragma unroll
      for (int kt = 6; kt < 8; ++kt) {
        const int tl = wave * 16 + gt * 4 + nh * 2 + (kt - 6);
        *(bf16x8*)(ldsB + ((size_t)tl * 64 + lane) * 8) = cvt8(wrow + kt * 32 + lq * 8);
      }
    }

  for (int i = threadIdx.x; i < 8192; i += 512) hbuf[i] = 0;
  float creg[2] = {0.f, 0.f};

  // output base: this thread's batch row is b0+lq, hidden col j0+lm (+nh*16)
  float* obase = out + (size_t)(b0 + lq) * T_LEN * 512 + dir * 256 + j0 + lm;

  // h write slot (A-frag-native): value (m=4*lq, col jfull=j0+nh*16+lm) ->
  // kt'=wave, quad'=nh*2+(lm>>3), row'=4*lq, e=lm&7; nh adds 256 shorts.
  const int wb0 = wave * 512 + (lm >> 3) * 128 + lq * 32 + (lm & 7);

  // prefetch xq for step 0 (one 16B load per thread per step)
  const int tt0 = dir ? (T_LEN - 1) : 0;
  bf16x8 xq_n = *(const bf16x8*)(xgd + ((((size_t)tt0 * 8 + bg) * 512 + threadIdx.x) << 3));

  __syncthreads();

  for (int s = 0; s < T_LEN; ++s) {
    const int tt = dir ? (T_LEN - 1 - s) : s;
    const unsigned short* hr = hbuf + (s & 1) * 4096;
    unsigned short* hw = hbuf + ((s + 1) & 1) * 4096;

    const bf16x8 xq = xq_n;   // consumed this step

    // issue prefetch for step s+1: latency spans the whole step
    const int s1 = (s + 1 < T_LEN) ? (s + 1) : s;
    const int tt1 = dir ? (T_LEN - 1 - s1) : s1;
    xq_n = *(const bf16x8*)(xgd + ((((size_t)tt1 * 8 + bg) * 512 + threadIdx.x) << 3));

    // A-frags for the reg-resident kts, held across both nh passes (24 VGPR)
    bf16x8 ar[6];
    #pragma unroll
    for (int kt = 0; kt < 6; ++kt)
      ar[kt] = *(const bf16x8*)(hr + kt * 512 + lane * 8);

    const size_t tto = (size_t)tt * 512;
    #pragma unroll
    for (int nh = 0; nh < 2; ++nh) {
      f32x4 acc[4];
      #pragma unroll
      for (int gt = 0; gt < 4; ++gt) acc[gt] = (f32x4){0.f, 0.f, 0.f, 0.f};

      __builtin_amdgcn_s_setprio(1);
      // LDS-resident kts first: B-frag reads issue early, latency hides
      #pragma unroll
      for (int kt = 6; kt < 8; ++kt) {
        const bf16x8 afrag = *(const bf16x8*)(hr + kt * 512 + lane * 8);
        #pragma unroll
        for (int gt = 0; gt < 4; ++gt) {
          const bf16x8 bfr = *(const bf16x8*)(ldsB + ((size_t)(wave * 16 + gt * 4 + nh * 2 + (kt - 6)) * 64 + lane) * 8);
          acc[gt] = __builtin_amdgcn_mfma_f32_16x16x32_bf16(afrag, bfr, acc[gt], 0, 0, 0);
        }
      }
      // reg-resident kts, gt-outer: acc[gt] completes after its own chain,
      // letting gate math start while later gates' MFMAs still run
      #pragma unroll
      for (int gt = 0; gt < 4; ++gt)
        #pragma unroll
        for (int kt = 0; kt < 6; ++kt)
          acc[gt] = __builtin_amdgcn_mfma_f32_16x16x32_bf16(ar[kt], breg[gt][nh][kt], acc[gt], 0, 0, 0);
      __builtin_amdgcn_s_setprio(0);

      const float iv = sigm(acc[0][0] + h2f((unsigned short)xq[nh * 4 + 0]));
      const float fv = sigm(acc[1][0] + h2f((unsigned short)xq[nh * 4 + 1]));
      const float gv = tanh_fast(acc[2][0] + h2f((unsigned short)xq[nh * 4 + 2]));
      const float ov = sigm(acc[3][0] + h2f((unsigned short)xq[nh * 4 + 3]));
      const float cv = fv * creg[nh] + iv * gv;
      creg[nh] = cv;
      const float hv = ov * tanh_fast(cv);
      hw[wb0 + nh * 256] = f2bf(hv);
      obase[tto + nh * 16] = hv;
    }

    // LDS-only fence + raw barrier: global stores/load stay in flight.
    asm volatile("s_waitcnt lgkmcnt(0)" ::: "memory");
    __builtin_amdgcn_s_barrier();
  }
}

// ---------------------------------------------------------------------------
extern "C" void kernel_launch(void* const* d_in, const int* in_sizes, int n_in,
                              void* d_out, int out_size, void* d_ws, size_t ws_size,
                              hipStream_t stream) {
  const float* x     = (const float*)d_in[0];
  const float* wih0f = (const float*)d_in[1];
  const float* whh0f = (const float*)d_in[2];
  const float* b0f   = (const float*)d_in[3];
  const float* wih0b = (const float*)d_in[4];
  const float* whh0b = (const float*)d_in[5];
  const float* b0b   = (const float*)d_in[6];
  const float* wih1f = (const float*)d_in[7];
  const float* whh1f = (const float*)d_in[8];
  const float* b1f   = (const float*)d_in[9];
  const float* wih1b = (const float*)d_in[10];
  const float* whh1b = (const float*)d_in[11];
  const float* b1b   = (const float*)d_in[12];
  float* out = (float*)d_out;

  // ws: xg only — [2][T][8][512][8] f16 = 64 MiB. Layer-0 hidden states are
  // routed through d_out (f32, fully overwritten by the layer-1 recurrence).
  unsigned short* xg = (unsigned short*)d_ws;

  gemm_xg<<<dim3(256, 16, 2), 256, 0, stream>>>(x,   wih0f, wih0b, b0f, b0b, xg, 256);
  lstm_rec<<<16, 512, 0, stream>>>(xg, whh0f, whh0b, out);   // h1 -> d_out (f32)
  gemm_xg<<<dim3(256, 16, 2), 256, 0, stream>>>(out, wih1f, wih1b, b1f, b1b, xg, 512);
  lstm_rec<<<16, 512, 0, stream>>>(xg, whh1f, whh1b, out);
}